// Round 10
// baseline (202.067 us; speedup 1.0000x reference)
//
#include <hip/hip_runtime.h>
#include <stdint.h>

typedef __attribute__((ext_vector_type(8))) short  bf16x8;
typedef __attribute__((ext_vector_type(4))) float  f32x4;
typedef __attribute__((ext_vector_type(4))) int    int4v;
typedef __attribute__((ext_vector_type(4))) float  float4v;
typedef __attribute__((ext_vector_type(4))) unsigned int uint4v;
typedef __attribute__((ext_vector_type(2))) unsigned int uint2v;

#define NN   8192   // nodes
#define DIN  512
#define DOUT 256
#define NW   (NN / 32)   // 256 dwords of bits per row

// k_agg geometry: BM=128, BN=256, BK=64, KSPLIT=8 -> grid 512 (2 blocks/CU)
#define BM2     128
#define KSPLIT2 8
#define KS2     (NN / KSPLIT2)  // 1024
#define BK2     64
#define NTK     (KS2 / BK2)     // 16

#define MFMA16(a, b, c) __builtin_amdgcn_mfma_f32_16x16x32_bf16((a), (b), (c), 0, 0, 0)

__device__ __forceinline__ unsigned short f2bf(float f) {
  unsigned u = __float_as_uint(f);
  return (unsigned short)((u + 0x7FFFu + ((u >> 16) & 1u)) >> 16);
}

__device__ __forceinline__ void gld16(const void* g, void* s) {
  __builtin_amdgcn_global_load_lds(
      (const __attribute__((address_space(1))) unsigned int*)g,
      (__attribute__((address_space(3))) unsigned int*)s, 16, 0, 0);
}

// ---------------------------------------------------------------------------
// Kernel 0: Wt[n][c] = bf16(W[c][n]).  W: [512][256] f32 -> Wt: [256][512] bf16
// ---------------------------------------------------------------------------
__global__ void k_wt(const float* __restrict__ W, unsigned short* __restrict__ Wt) {
  int n = blockIdx.x; // 0..255
  for (int c = threadIdx.x; c < DIN; c += blockDim.x)
    Wt[n * DIN + c] = f2bf(W[c * DOUT + n]);
}

// ---------------------------------------------------------------------------
// Kernel 1: xw_t[n][m] = sum_c x[m][c] * W[c][n]   (bf16 out, transposed)
// ---------------------------------------------------------------------------
__global__ __launch_bounds__(256) void k_xwt(const float* __restrict__ x,
                                             const unsigned short* __restrict__ Wt,
                                             unsigned short* __restrict__ xw_t) {
  const int mb = blockIdx.x >> 1, nb = blockIdx.x & 1;
  const int tid = threadIdx.x;
  const int w = tid >> 6, l = tid & 63;
  const int wm = w >> 1, wn = w & 1;
  const int lr = l & 15, lg = l >> 4;
  const int m_base = mb * 128 + wm * 64;
  const int n_base = nb * 128 + wn * 64;

  f32x4 acc[4][4];
  for (int i = 0; i < 4; ++i)
    for (int j = 0; j < 4; ++j) acc[i][j] = (f32x4)0.0f;

  for (int c0 = 0; c0 < DIN; c0 += 32) {
    const int c = c0 + lg * 8;
    bf16x8 af[4], bfv[4];
#pragma unroll
    for (int mt = 0; mt < 4; ++mt) {
      const float* xp = x + (size_t)(m_base + mt * 16 + lr) * DIN + c;
      float4v x0 = *reinterpret_cast<const float4v*>(xp);
      float4v x1 = *reinterpret_cast<const float4v*>(xp + 4);
      bf16x8 a;
#pragma unroll
      for (int j = 0; j < 4; ++j) {
        a[j]     = (short)f2bf(x0[j]);
        a[4 + j] = (short)f2bf(x1[j]);
      }
      af[mt] = a;
    }
#pragma unroll
    for (int nt = 0; nt < 4; ++nt)
      bfv[nt] = *reinterpret_cast<const bf16x8*>(Wt + (size_t)(n_base + nt * 16 + lr) * DIN + c);
#pragma unroll
    for (int mt = 0; mt < 4; ++mt)
#pragma unroll
      for (int nt = 0; nt < 4; ++nt)
        acc[mt][nt] = MFMA16(af[mt], bfv[nt], acc[mt][nt]);
  }

#pragma unroll
  for (int nt = 0; nt < 4; ++nt) {
    const int n = n_base + nt * 16 + lr;
#pragma unroll
    for (int mt = 0; mt < 4; ++mt) {
      const int m = m_base + mt * 16 + lg * 4;
      unsigned short b0 = f2bf(acc[mt][nt][0]), b1 = f2bf(acc[mt][nt][1]);
      unsigned short b2 = f2bf(acc[mt][nt][2]), b3 = f2bf(acc[mt][nt][3]);
      uint2v p;
      p[0] = (unsigned)b0 | ((unsigned)b1 << 16);
      p[1] = (unsigned)b2 | ((unsigned)b3 << 16);
      *reinterpret_cast<uint2v*>(xw_t + (size_t)n * NN + m) = p;
    }
  }
}

// ---------------------------------------------------------------------------
// Kernel 2: pack adj -> bits + deg via wave ballot (unchanged from r7/r8).
// ---------------------------------------------------------------------------
__global__ __launch_bounds__(256) void k_pack(const int* __restrict__ adj,
                                              unsigned int* __restrict__ bits,
                                              int* __restrict__ deg) {
  __shared__ int wsum[4];
  const int tid = threadIdx.x;
  const int w = tid >> 6, l = tid & 63;
  const int row = blockIdx.x;
  const int* src = adj + (size_t)row * NN + w * 2048 + l;
  unsigned long long* bdst =
      reinterpret_cast<unsigned long long*>(bits + (size_t)row * NW + w * 64);

  int cnt = 0;
#pragma unroll
  for (int it = 0; it < 32; it += 8) {
    unsigned long long b[8];
#pragma unroll
    for (int u = 0; u < 8; ++u)
      b[u] = __ballot(src[(it + u) * 64] != 0);
#pragma unroll
    for (int u = 0; u < 8; ++u) {
      if (l == 0) bdst[it + u] = b[u];
      cnt += (int)__popcll(b[u]);
    }
  }

  if (l == 0) wsum[w] = cnt;
  __syncthreads();
  if (tid == 0) deg[row] = wsum[0] + wsum[1] + wsum[2] + wsum[3];
}

// ---------------------------------------------------------------------------
// Kernel 3: split-K partial  outp[ks] = A_bits[rows,kslice] * xw[kslice,:]
// IDENTICAL to round 8. Launched TWICE this round (idempotent: exclusive
// partial stores, no atomics) purely to measure its duration as
// dur_us(total) - 151.5. No other change anywhere.
// ---------------------------------------------------------------------------
__global__ __launch_bounds__(512, 4) void k_agg(const unsigned int* __restrict__ bits,
                                                const unsigned short* __restrict__ xw_t,
                                                float* __restrict__ outp) {
  __shared__ unsigned short Bs[2][16384]; // 32 KB per buffer

  const int tid = threadIdx.x;
  const int w = tid >> 6, l = tid & 63;
  const int lr = l & 15, lg = l >> 4;
  const int wm = w >> 2, wn = w & 3;

  const int bid = blockIdx.x;
  const int ks = bid & 7;        // XCD pin
  const int rb = bid >> 3;       // 0..63
  const int row0 = rb * BM2;

  const int sn = tid >> 3;
  const int sj = tid & 7;
  const unsigned short* gB = xw_t + (size_t)sn * NN + ks * KS2 + ((sj ^ (sn & 7)) * 8);

  const unsigned int* gA = bits + (size_t)(row0 + wm * 64 + lr) * NW + ks * (KS2 >> 5);

  f32x4 acc[4][4];
#pragma unroll
  for (int i = 0; i < 4; ++i)
#pragma unroll
    for (int j = 0; j < 4; ++j) acc[i][j] = (f32x4)0.0f;

  uint2v Ab[4], An[4];

#define STAGE_B(t, buf) do {                                                   \
    _Pragma("unroll")                                                          \
    for (int p_ = 0; p_ < 4; ++p_)                                             \
      gld16(gB + (size_t)p_ * 64 * NN + (t) * BK2,                             \
            (char*)&Bs[buf][0] + p_ * 8192 + w * 1024);                        \
  } while (0)

#define LOADA(t, arr) do {                                                     \
    _Pragma("unroll")                                                          \
    for (int mf_ = 0; mf_ < 4; ++mf_)                                          \
      arr[mf_] = *reinterpret_cast<const uint2v*>(gA + (size_t)mf_ * 16 * NW + 2 * (t)); \
  } while (0)

#define COMPUTE(buf) do {                                                      \
    _Pragma("unroll")                                                          \
    for (int kf_ = 0; kf_ < 2; ++kf_) {                                        \
      bf16x8 bf_[4];                                                           \
      _Pragma("unroll")                                                        \
      for (int nf_ = 0; nf_ < 4; ++nf_) {                                      \
        const int n_ = wn * 64 + nf_ * 16 + lr;                                \
        bf_[nf_] = *reinterpret_cast<const bf16x8*>(                           \
            &Bs[buf][n_ * 64 + (((kf_ * 4 + lg) ^ (n_ & 7)) * 8)]);            \
      }                                                                        \
      _Pragma("unroll")                                                        \
      for (int mf_ = 0; mf_ < 4; ++mf_) {                                      \
        const unsigned a32_ = Ab[mf_][kf_];                                    \
        uint4v q_;                                                             \
        _Pragma("unroll")                                                      \
        for (int j_ = 0; j_ < 4; ++j_) {                                       \
          unsigned b2_ = (a32_ >> (lg * 8 + 2 * j_)) & 3u;                     \
          q_[j_] = ((b2_ | (b2_ << 15)) & 0x10001u) * 0x3F80u;                 \
        }                                                                      \
        const bf16x8 af_ = *reinterpret_cast<const bf16x8*>(&q_);              \
        acc[mf_][0] = MFMA16(af_, bf_[0], acc[mf_][0]);                        \
        acc[mf_][1] = MFMA16(af_, bf_[1], acc[mf_][1]);                        \
        acc[mf_][2] = MFMA16(af_, bf_[2], acc[mf_][2]);                        \
        acc[mf_][3] = MFMA16(af_, bf_[3], acc[mf_][3]);                        \
      }                                                                        \
    }                                                                          \
  } while (0)

  STAGE_B(0, 0);
  LOADA(0, Ab);
  __syncthreads();

  for (int t = 0; t < NTK; ++t) {
    const int buf = t & 1;
    if (t + 1 < NTK) {
      STAGE_B(t + 1, buf ^ 1);
      LOADA(t + 1, An);
    }
    COMPUTE(buf);
#pragma unroll
    for (int mf = 0; mf < 4; ++mf) Ab[mf] = An[mf];
    __syncthreads();
  }
#undef STAGE_B
#undef LOADA
#undef COMPUTE

  float* po = outp + (size_t)ks * NN * DOUT;
#pragma unroll
  for (int mf = 0; mf < 4; ++mf)
#pragma unroll
    for (int nf = 0; nf < 4; ++nf)
#pragma unroll
      for (int r = 0; r < 4; ++r) {
        const int row = row0 + wm * 64 + mf * 16 + lg * 4 + r;
        const int col = wn * 64 + nf * 16 + lr;
        po[(size_t)row * DOUT + col] = acc[mf][nf][r];
      }
}

// ---------------------------------------------------------------------------
// Kernel 4: out = (sum_ks outp[ks]) / deg
// ---------------------------------------------------------------------------
__global__ __launch_bounds__(256) void k_div(const float* __restrict__ outp,
                                             const int* __restrict__ deg,
                                             float* __restrict__ out) {
  const int idx = blockIdx.x * 256 + threadIdx.x;
  const size_t i4 = (size_t)idx * 4;
  const int row = (int)(i4 >> 8); // DOUT=256
  float4v s = *reinterpret_cast<const float4v*>(outp + i4);
#pragma unroll
  for (int p = 1; p < KSPLIT2; ++p) {
    float4v v = *reinterpret_cast<const float4v*>(outp + (size_t)p * NN * DOUT + i4);
    s[0] += v[0]; s[1] += v[1]; s[2] += v[2]; s[3] += v[3];
  }
  const float sc = 1.0f / (float)deg[row];
  s[0] *= sc; s[1] *= sc; s[2] *= sc; s[3] *= sc;
  *reinterpret_cast<float4v*>(out + i4) = s;
}

// ---------------------------------------------------------------------------
extern "C" void kernel_launch(void* const* d_in, const int* in_sizes, int n_in,
                              void* d_out, int out_size, void* d_ws, size_t ws_size,
                              hipStream_t stream) {
  const float* x   = (const float*)d_in[0]; // [8192][512] f32
  const int*   adj = (const int*)d_in[1];   // [8192][8192] i32 (0/1)
  const float* W   = (const float*)d_in[2]; // [512][256] f32
  float* out = (float*)d_out;               // [8192][256] f32

  char* ws = (char*)d_ws;
  unsigned short* xw_t = (unsigned short*)ws;                               // 4 MB
  unsigned short* Wt   = (unsigned short*)(ws + (size_t)4 * 1024 * 1024);   // 256 KB
  int*            deg  = (int*)(ws + (size_t)4 * 1024 * 1024 + 512 * 1024); // 32 KB
  unsigned int*   bits = (unsigned int*)(ws + (size_t)5 * 1024 * 1024);     // 8 MB
  float*          outp = (float*)(ws + (size_t)16 * 1024 * 1024);           // 64 MB

  k_wt<<<256, 128, 0, stream>>>(W, Wt);
  k_xwt<<<128, 256, 0, stream>>>(x, Wt, xw_t);
  k_pack<<<NN, 256, 0, stream>>>(adj, bits, deg);
  // Attribution: k_agg launched twice (idempotent). G = dur_us - 151.5.
  k_agg<<<(NN / BM2) * KSPLIT2, 512, 0, stream>>>(bits, xw_t, outp);
  k_agg<<<(NN / BM2) * KSPLIT2, 512, 0, stream>>>(bits, xw_t, outp);
  k_div<<<(NN * DOUT) / (256 * 4), 256, 0, stream>>>(outp, deg, out);
}

// Round 11
// 180.225 us; speedup vs baseline: 1.1212x; 1.1212x over previous
//
#include <hip/hip_runtime.h>
#include <stdint.h>

typedef __attribute__((ext_vector_type(8))) short  bf16x8;
typedef __attribute__((ext_vector_type(4))) float  f32x4;
typedef __attribute__((ext_vector_type(4))) int    int4v;
typedef __attribute__((ext_vector_type(4))) float  float4v;
typedef __attribute__((ext_vector_type(4))) unsigned int uint4v;
typedef __attribute__((ext_vector_type(2))) unsigned int uint2v;

#define NN   8192   // nodes
#define DIN  512
#define DOUT 256

// fused k_agg geometry: BM=256, BN=256(full), BK=64, KSPLIT=8
// grid 256 = 32 rb x 8 ks -> 1 block/CU, single pass
#define BM2     256
#define KSPLIT2 8
#define KS2     (NN / KSPLIT2)  // 1024
#define BK2     64
#define NTK     (KS2 / BK2)     // 16

#define MFMA16(a, b, c) __builtin_amdgcn_mfma_f32_16x16x32_bf16((a), (b), (c), 0, 0, 0)
// two 0/1 ints -> packed dword of two bf16 (0.0 / 1.0)
#define PK2(a, b) (((0u - (unsigned)(a)) & 0x3F80u) | (((0u - (unsigned)(b)) & 0x3F80u) << 16))

__device__ __forceinline__ unsigned short f2bf(float f) {
  unsigned u = __float_as_uint(f);
  return (unsigned short)((u + 0x7FFFu + ((u >> 16) & 1u)) >> 16);
}

__device__ __forceinline__ void gld16(const void* g, void* s) {
  __builtin_amdgcn_global_load_lds(
      (const __attribute__((address_space(1))) unsigned int*)g,
      (__attribute__((address_space(3))) unsigned int*)s, 16, 0, 0);
}

// ---------------------------------------------------------------------------
// Kernel 0: Wt[n][c] = bf16(W[c][n])
// ---------------------------------------------------------------------------
__global__ void k_wt(const float* __restrict__ W, unsigned short* __restrict__ Wt) {
  int n = blockIdx.x; // 0..255
  for (int c = threadIdx.x; c < DIN; c += blockDim.x)
    Wt[n * DIN + c] = f2bf(W[c * DOUT + n]);
}

// ---------------------------------------------------------------------------
// Kernel 1: xw_t[n][m] = sum_c x[m][c] * W[c][n]   (bf16 out, transposed)
// ---------------------------------------------------------------------------
__global__ __launch_bounds__(256) void k_xwt(const float* __restrict__ x,
                                             const unsigned short* __restrict__ Wt,
                                             unsigned short* __restrict__ xw_t) {
  const int mb = blockIdx.x >> 1, nb = blockIdx.x & 1;
  const int tid = threadIdx.x;
  const int w = tid >> 6, l = tid & 63;
  const int wm = w >> 1, wn = w & 1;
  const int lr = l & 15, lg = l >> 4;
  const int m_base = mb * 128 + wm * 64;
  const int n_base = nb * 128 + wn * 64;

  f32x4 acc[4][4];
  for (int i = 0; i < 4; ++i)
    for (int j = 0; j < 4; ++j) acc[i][j] = (f32x4)0.0f;

  for (int c0 = 0; c0 < DIN; c0 += 32) {
    const int c = c0 + lg * 8;
    bf16x8 af[4], bfv[4];
#pragma unroll
    for (int mt = 0; mt < 4; ++mt) {
      const float* xp = x + (size_t)(m_base + mt * 16 + lr) * DIN + c;
      float4v x0 = *reinterpret_cast<const float4v*>(xp);
      float4v x1 = *reinterpret_cast<const float4v*>(xp + 4);
      bf16x8 a;
#pragma unroll
      for (int j = 0; j < 4; ++j) {
        a[j]     = (short)f2bf(x0[j]);
        a[4 + j] = (short)f2bf(x1[j]);
      }
      af[mt] = a;
    }
#pragma unroll
    for (int nt = 0; nt < 4; ++nt)
      bfv[nt] = *reinterpret_cast<const bf16x8*>(Wt + (size_t)(n_base + nt * 16 + lr) * DIN + c);
#pragma unroll
    for (int mt = 0; mt < 4; ++mt)
#pragma unroll
      for (int nt = 0; nt < 4; ++nt)
        acc[mt][nt] = MFMA16(af[mt], bfv[nt], acc[mt][nt]);
  }

#pragma unroll
  for (int nt = 0; nt < 4; ++nt) {
    const int n = n_base + nt * 16 + lr;
#pragma unroll
    for (int mt = 0; mt < 4; ++mt) {
      const int m = m_base + mt * 16 + lg * 4;
      unsigned short b0 = f2bf(acc[mt][nt][0]), b1 = f2bf(acc[mt][nt][1]);
      unsigned short b2 = f2bf(acc[mt][nt][2]), b3 = f2bf(acc[mt][nt][3]);
      uint2v p;
      p[0] = (unsigned)b0 | ((unsigned)b1 << 16);
      p[1] = (unsigned)b2 | ((unsigned)b3 << 16);
      *reinterpret_cast<uint2v*>(xw_t + (size_t)n * NN + m) = p;
    }
  }
}

// ---------------------------------------------------------------------------
// Kernel 2 (FUSED pack+agg): outp[ks] = A[rows,kslice] * xw[kslice,:], degp.
// Reads RAW adj exactly once (268 MB HBM stream). Per tile:
//   raw A -> regs (coalesced 64 B/thread) ; B -> LDS via gld16 ;
//   COMPUTE (pure ds_read+MFMA) ; convert A(t+1) via PK2 + swizzled ds_write ;
//   one barrier. deg partials accumulated at conversion (each elem once).
// BM=256, KSPLIT=8, grid 256 (1 block/CU, 1 pass), block 512 = 8 waves
// (2 wm x 4 wn), wave = 128m x 64n. LDS 128 KB (A 2x32 + B 2x32).
// ---------------------------------------------------------------------------
__global__ __launch_bounds__(512, 2) void k_agg(const int* __restrict__ adj,
                                                const unsigned short* __restrict__ xw_t,
                                                float* __restrict__ outp,
                                                int* __restrict__ degp) {
  __shared__ unsigned short Abf[2][BM2 * 64]; // 32 KB each, bf16, swizzled rows of 8 blocks
  __shared__ unsigned short Bs[2][16384];     // 32 KB each

  const int tid = threadIdx.x;
  const int w = tid >> 6, l = tid & 63;
  const int lr = l & 15, lg = l >> 4;
  const int wm = w >> 2, wn = w & 3;

  const int bid = blockIdx.x;
  const int ks = bid & 7;        // XCD pin
  const int rb = bid >> 3;       // 0..31
  const int row0 = rb * BM2;
  const int kbase = ks * KS2;

  // A raw staging: thread -> row sr, 32 ints at col c2*32 (128 B contiguous)
  const int sr = tid >> 1;
  const int c2 = tid & 1;
  const int* gApt = adj + (size_t)(row0 + sr) * NN + kbase + c2 * 32;

  // B staging (r8 pattern, pre-swizzled source)
  const int sn = tid >> 3;
  const int sj = tid & 7;
  const unsigned short* gB = xw_t + (size_t)sn * NN + kbase + ((sj ^ (sn & 7)) * 8);

  f32x4 acc[8][4];
#pragma unroll
  for (int i = 0; i < 8; ++i)
#pragma unroll
    for (int j = 0; j < 4; ++j) acc[i][j] = (f32x4)0.0f;

  int4v ar[8]; // raw tile: 32 ints
  int cnt = 0;

#define LOAD_RAWA(t) do {                                                      \
    _Pragma("unroll")                                                          \
    for (int i_ = 0; i_ < 8; ++i_)                                             \
      ar[i_] = *reinterpret_cast<const int4v*>(gApt + (size_t)(t) * BK2 + i_ * 4); \
  } while (0)

#define STAGE_B(t, buf) do {                                                   \
    _Pragma("unroll")                                                          \
    for (int p_ = 0; p_ < 4; ++p_)                                             \
      gld16(gB + (size_t)p_ * 64 * NN + (t) * BK2,                             \
            (char*)&Bs[buf][0] + p_ * 8192 + w * 1024);                        \
  } while (0)

  // convert 32 raw ints -> 16 packed dwords -> 4 swizzled ds_write_b128;
  // count ones (each adj element converted exactly once per k-slice).
#define CVT_WRITE_A(buf) do {                                                  \
    _Pragma("unroll")                                                          \
    for (int i_ = 0; i_ < 8; ++i_)                                             \
      cnt += ar[i_][0] + ar[i_][1] + ar[i_][2] + ar[i_][3];                    \
    _Pragma("unroll")                                                          \
    for (int q_ = 0; q_ < 4; ++q_) {                                           \
      uint4v dq_;                                                              \
      _Pragma("unroll")                                                        \
      for (int j_ = 0; j_ < 4; ++j_) {                                         \
        const int d_ = q_ * 4 + j_;                                            \
        dq_[j_] = PK2(ar[d_ >> 1][(d_ & 1) * 2], ar[d_ >> 1][(d_ & 1) * 2 + 1]); \
      }                                                                        \
      const int bsw_ = ((c2 * 4 + q_) ^ (sr & 7)) * 8;                         \
      *reinterpret_cast<uint4v*>(&Abf[buf][sr * 64 + bsw_]) = dq_;             \
    }                                                                          \
  } while (0)

#define COMPUTE(buf) do {                                                      \
    _Pragma("unroll")                                                          \
    for (int kf_ = 0; kf_ < 2; ++kf_) {                                        \
      bf16x8 bf_[4];                                                           \
      _Pragma("unroll")                                                        \
      for (int nf_ = 0; nf_ < 4; ++nf_) {                                      \
        const int n_ = wn * 64 + nf_ * 16 + lr;                                \
        bf_[nf_] = *reinterpret_cast<const bf16x8*>(                           \
            &Bs[buf][n_ * 64 + (((kf_ * 4 + lg) ^ (n_ & 7)) * 8)]);            \
      }                                                                        \
      _Pragma("unroll")                                                        \
      for (int mf_ = 0; mf_ < 8; ++mf_) {                                      \
        const int r_ = wm * 128 + mf_ * 16 + lr;                               \
        const bf16x8 af_ = *reinterpret_cast<const bf16x8*>(                   \
            &Abf[buf][r_ * 64 + (((kf_ * 4 + lg) ^ (r_ & 7)) * 8)]);           \
        acc[mf_][0] = MFMA16(af_, bf_[0], acc[mf_][0]);                        \
        acc[mf_][1] = MFMA16(af_, bf_[1], acc[mf_][1]);                        \
        acc[mf_][2] = MFMA16(af_, bf_[2], acc[mf_][2]);                        \
        acc[mf_][3] = MFMA16(af_, bf_[3], acc[mf_][3]);                        \
      }                                                                        \
    }                                                                          \
  } while (0)

  // prologue: tile 0 fully staged
  LOAD_RAWA(0);
  STAGE_B(0, 0);
  CVT_WRITE_A(0);
  __syncthreads();

  for (int t = 0; t < NTK; ++t) {
    const int buf = t & 1;
    if (t + 1 < NTK) {
      LOAD_RAWA(t + 1);        // HBM stream, lands during compute
      STAGE_B(t + 1, buf ^ 1); // L2-resident slice
    }
    COMPUTE(buf);
    if (t + 1 < NTK) CVT_WRITE_A(buf ^ 1);
    __syncthreads();
  }
#undef LOAD_RAWA
#undef STAGE_B
#undef CVT_WRITE_A
#undef COMPUTE

  // deg partial: 2 threads per row
  cnt += __shfl_xor(cnt, 1);
  if (c2 == 0) degp[ks * NN + row0 + sr] = cnt;

  // exclusive partial store
  float* po = outp + (size_t)ks * NN * DOUT;
#pragma unroll
  for (int mf = 0; mf < 8; ++mf)
#pragma unroll
    for (int nf = 0; nf < 4; ++nf)
#pragma unroll
      for (int r = 0; r < 4; ++r) {
        const int row = row0 + wm * 128 + mf * 16 + lg * 4 + r;
        const int col = wn * 64 + nf * 16 + lr;
        po[(size_t)row * DOUT + col] = acc[mf][nf][r];
      }
}

// ---------------------------------------------------------------------------
// Kernel 3: out = (sum_ks outp[ks]) / (sum_ks degp[ks])
// ---------------------------------------------------------------------------
__global__ __launch_bounds__(256) void k_div(const float* __restrict__ outp,
                                             const int* __restrict__ degp,
                                             float* __restrict__ out) {
  const int idx = blockIdx.x * 256 + threadIdx.x;
  const size_t i4 = (size_t)idx * 4;
  const int row = (int)(i4 >> 8); // DOUT=256
  float4v s = *reinterpret_cast<const float4v*>(outp + i4);
#pragma unroll
  for (int p = 1; p < KSPLIT2; ++p) {
    float4v v = *reinterpret_cast<const float4v*>(outp + (size_t)p * NN * DOUT + i4);
    s[0] += v[0]; s[1] += v[1]; s[2] += v[2]; s[3] += v[3];
  }
  int d = 0;
#pragma unroll
  for (int p = 0; p < KSPLIT2; ++p) d += degp[p * NN + row];
  const float sc = 1.0f / (float)d;
  s[0] *= sc; s[1] *= sc; s[2] *= sc; s[3] *= sc;
  *reinterpret_cast<float4v*>(out + i4) = s;
}

// ---------------------------------------------------------------------------
extern "C" void kernel_launch(void* const* d_in, const int* in_sizes, int n_in,
                              void* d_out, int out_size, void* d_ws, size_t ws_size,
                              hipStream_t stream) {
  const float* x   = (const float*)d_in[0]; // [8192][512] f32
  const int*   adj = (const int*)d_in[1];   // [8192][8192] i32 (0/1)
  const float* W   = (const float*)d_in[2]; // [512][256] f32
  float* out = (float*)d_out;               // [8192][256] f32

  char* ws = (char*)d_ws;
  unsigned short* xw_t = (unsigned short*)ws;                               // 4 MB
  unsigned short* Wt   = (unsigned short*)(ws + (size_t)4 * 1024 * 1024);   // 256 KB
  int*            degp = (int*)(ws + (size_t)4 * 1024 * 1024 + 512 * 1024); // 256 KB (8 x 8192)
  float*          outp = (float*)(ws + (size_t)16 * 1024 * 1024);           // 64 MB (8 x 8 MB)

  k_wt<<<256, 128, 0, stream>>>(W, Wt);
  k_xwt<<<128, 256, 0, stream>>>(x, Wt, xw_t);
  k_agg<<<(NN / BM2) * KSPLIT2, 512, 0, stream>>>(adj, xw_t, outp, degp);
  k_div<<<(NN * DOUT) / (256 * 4), 256, 0, stream>>>(outp, degp, out);
}